// Round 1
// baseline (1212.328 us; speedup 1.0000x reference)
//
#include <hip/hip_runtime.h>
#include <math.h>

#define N_NODES  100000
#define N_EDGES  3200000
#define N_GRAPHS 256
#define F        64

// JAX default gelu: approximate=True (tanh form)
__device__ __forceinline__ float gelu_f(float x) {
    float x3 = x * x * x;
    float inner = 0.7978845608028654f * (x + 0.044715f * x3);
    return 0.5f * x * (1.0f + tanhf(inner));
}

// ---- CSR build ------------------------------------------------------------

__global__ void k_hist(const int* __restrict__ col, const float* __restrict__ ew,
                       float* __restrict__ deg, int* __restrict__ cnt) {
    int e = blockIdx.x * blockDim.x + threadIdx.x;
    if (e < N_EDGES) {
        int c = col[e];
        atomicAdd(&cnt[c], 1);
        atomicAdd(&deg[c], ew[e]);
    }
}

__global__ void k_dinv(float* deg) {
    int n = blockIdx.x * blockDim.x + threadIdx.x;
    if (n < N_NODES) deg[n] = rsqrtf(deg[n] + 1.0f);  // +1 = self-loop weight
}

// single-block 3-phase exclusive scan of cnt -> offs (and cursor copy)
__global__ void __launch_bounds__(1024) k_scan(const int* __restrict__ cnt,
                                               int* __restrict__ offs,
                                               int* __restrict__ cursor) {
    __shared__ int sums[1024];
    int t = threadIdx.x;
    const int chunk = (N_NODES + 1023) / 1024;
    int b = t * chunk;
    int e = min(b + chunk, N_NODES);
    int s = 0;
    for (int i = b; i < e; i++) s += cnt[i];
    sums[t] = s;
    __syncthreads();
    for (int off = 1; off < 1024; off <<= 1) {
        int v = 0;
        if (t >= off) v = sums[t - off];
        __syncthreads();
        if (t >= off) sums[t] += v;
        __syncthreads();
    }
    int run = sums[t] - s;  // exclusive prefix for this thread's range
    for (int i = b; i < e; i++) {
        int c = cnt[i];
        offs[i] = run;
        cursor[i] = run;
        run += c;
    }
    if (t == 1023) offs[N_NODES] = sums[1023];
}

__global__ void k_scatter(const int* __restrict__ row, const int* __restrict__ col,
                          const float* __restrict__ ew, const float* __restrict__ dinv,
                          int* __restrict__ cursor, int* __restrict__ esrc,
                          float* __restrict__ ewn) {
    int e = blockIdx.x * blockDim.x + threadIdx.x;
    if (e < N_EDGES) {
        int c = col[e];
        int r = row[e];
        int p = atomicAdd(&cursor[c], 1);
        esrc[p] = r;
        ewn[p]  = dinv[r] * ew[e] * dinv[c];
    }
}

// ---- Layer 1 (scalar aggregation, then expand by W1) ----------------------

__global__ void k_s1(const float* __restrict__ x, const float* __restrict__ dinv,
                     const int* __restrict__ offs, const int* __restrict__ esrc,
                     const float* __restrict__ ewn, float* __restrict__ s1) {
    int c = blockIdx.x * blockDim.x + threadIdx.x;
    if (c >= N_NODES) return;
    float d = dinv[c];
    float s = d * d * x[c];
    int b = offs[c], e = offs[c + 1];
    for (int j = b; j < e; j++) s = fmaf(ewn[j], x[esrc[j]], s);
    s1[c] = s;
}

__global__ void k_h1(const float* __restrict__ s1, const float* __restrict__ W1,
                     const float* __restrict__ b1, float* __restrict__ h1) {
    int i = blockIdx.x * blockDim.x + threadIdx.x;
    if (i >= N_NODES * F) return;
    int f = i & (F - 1);
    int c = i >> 6;
    h1[i] = gelu_f(fmaf(s1[c], W1[f], b1[f]));
}

// ---- Layer 2 aggregation: one wave per node, lane = feature ---------------

__global__ void __launch_bounds__(256) k_agg(const float* __restrict__ h1,
                                             const float* __restrict__ dinv,
                                             const int* __restrict__ offs,
                                             const int* __restrict__ esrc,
                                             const float* __restrict__ ewn,
                                             float* __restrict__ a1) {
    int wave = (blockIdx.x * 256 + threadIdx.x) >> 6;
    int lane = threadIdx.x & 63;
    if (wave >= N_NODES) return;
    int c = wave;
    float d = dinv[c];
    float acc0 = d * d * h1[c * F + lane];
    float acc1 = 0.0f;
    int b = offs[c], e = offs[c + 1];
    int j = b;
    for (; j + 1 < e; j += 2) {
        int   s0 = esrc[j],     ss1 = esrc[j + 1];
        float w0 = ewn[j],      w1  = ewn[j + 1];
        acc0 = fmaf(w0, h1[s0 * F + lane], acc0);
        acc1 = fmaf(w1, h1[ss1 * F + lane], acc1);
    }
    if (j < e) acc0 = fmaf(ewn[j], h1[esrc[j] * F + lane], acc0);
    a1[c * F + lane] = acc0 + acc1;
}

// ---- Layer 2 matmul [N,64]@[64,64] + bias + gelu --------------------------

__global__ void __launch_bounds__(256) k_h2(const float* __restrict__ a1,
                                            const float* __restrict__ W2,
                                            const float* __restrict__ b2,
                                            float* __restrict__ h2) {
    __shared__ float sW[F * F];
    __shared__ float sb[F];
    __shared__ float sa[4][F];
    for (int i = threadIdx.x; i < F * F; i += 256) sW[i] = W2[i];
    if (threadIdx.x < F) sb[threadIdx.x] = b2[threadIdx.x];
    __syncthreads();
    int lane = threadIdx.x & 63;
    int wv   = threadIdx.x >> 6;
    for (int node = blockIdx.x * 4 + wv; node < N_NODES; node += gridDim.x * 4) {
        sa[wv][lane] = a1[node * F + lane];   // same-wave write/read: no barrier needed
        float acc = sb[lane];
#pragma unroll
        for (int k = 0; k < F; k++) acc = fmaf(sa[wv][k], sW[k * F + lane], acc);
        h2[node * F + lane] = gelu_f(acc);
    }
}

// ---- Pooling: batch is sorted -> run-length accumulate, rare atomics ------

__global__ void __launch_bounds__(256) k_pool(const float* __restrict__ h2,
                                              const int* __restrict__ batch,
                                              float* __restrict__ gsum,
                                              float* __restrict__ gcnt) {
    int gw   = (blockIdx.x * 256 + threadIdx.x) >> 6;  // global wave id
    int lane = threadIdx.x & 63;
    const int CHUNK = 256;
    int n0 = gw * CHUNK;
    if (n0 >= N_NODES) return;
    int n1 = min(n0 + CHUNK, N_NODES);
    int curg = batch[n0];
    float run = 0.0f;
    int   rl  = 0;
    for (int n = n0; n < n1; n++) {
        int g = batch[n];
        if (g != curg) {
            atomicAdd(&gsum[curg * F + lane], run);
            if (lane == 0) atomicAdd(&gcnt[curg], (float)rl);
            run = 0.0f; rl = 0; curg = g;
        }
        run += h2[n * F + lane];
        rl++;
    }
    atomicAdd(&gsum[curg * F + lane], run);
    if (lane == 0) atomicAdd(&gcnt[curg], (float)rl);
}

// ---- Final MLP: one wave per graph ----------------------------------------

__global__ void __launch_bounds__(256) k_final(const float* __restrict__ gsum,
                                               const float* __restrict__ gcnt,
                                               const float* __restrict__ fc1W,
                                               const float* __restrict__ fc1b,
                                               const float* __restrict__ fc2W,
                                               const float* __restrict__ fc2b,
                                               float* __restrict__ out) {
    __shared__ float sm[4][F];
    int lane = threadIdx.x & 63;
    int wv   = threadIdx.x >> 6;
    int g = blockIdx.x * 4 + wv;
    if (g >= N_GRAPHS) return;
    float c = gcnt[g];
    float m = gsum[g * F + lane] / fmaxf(c, 1.0f);
    sm[wv][lane] = m;  // same-wave write/read
    float o = 0.0f;
    if (lane < 32) {
        float acc = fc1b[lane];
#pragma unroll
        for (int k = 0; k < F; k++) acc = fmaf(sm[wv][k], fc1W[k * 32 + lane], acc);
        o = gelu_f(acc) * fc2W[lane];
    }
    for (int off = 32; off; off >>= 1) o += __shfl_down(o, off);
    if (lane == 0) out[g] = o + fc2b[0];
}

// ---------------------------------------------------------------------------

extern "C" void kernel_launch(void* const* d_in, const int* in_sizes, int n_in,
                              void* d_out, int out_size, void* d_ws, size_t ws_size,
                              hipStream_t stream) {
    const float* x    = (const float*)d_in[0];
    const int*   ei   = (const int*)  d_in[1];   // [2, E]
    const float* ea   = (const float*)d_in[2];
    const int*   bat  = (const int*)  d_in[3];
    const float* W1   = (const float*)d_in[4];
    const float* b1   = (const float*)d_in[5];
    const float* W2   = (const float*)d_in[6];
    const float* b2   = (const float*)d_in[7];
    const float* fc1W = (const float*)d_in[8];
    const float* fc1b = (const float*)d_in[9];
    const float* fc2W = (const float*)d_in[10];
    const float* fc2b = (const float*)d_in[11];
    float* out = (float*)d_out;

    const int* row = ei;
    const int* col = ei + N_EDGES;

    // workspace carve-up (256B aligned)
    size_t off = 0;
    auto alloc = [&](size_t bytes) -> void* {
        void* p = (char*)d_ws + off;
        off = (off + bytes + 255) & ~(size_t)255;
        return p;
    };
    float* deg    = (float*)alloc(N_NODES * 4);          // becomes dinv in-place
    int*   cnt    = (int*)  alloc(N_NODES * 4);
    int*   offs   = (int*)  alloc((N_NODES + 1) * 4);
    int*   cursor = (int*)  alloc(N_NODES * 4);
    int*   esrc   = (int*)  alloc((size_t)N_EDGES * 4);
    float* ewn    = (float*)alloc((size_t)N_EDGES * 4);
    float* s1     = (float*)alloc(N_NODES * 4);
    float* h1     = (float*)alloc((size_t)N_NODES * F * 4);   // reused as h2
    float* a1     = (float*)alloc((size_t)N_NODES * F * 4);
    float* gsum   = (float*)alloc(N_GRAPHS * F * 4);
    float* gcnt   = (float*)alloc(N_GRAPHS * 4);
    (void)ws_size; (void)n_in; (void)in_sizes; (void)out_size;

    hipMemsetAsync(deg,  0, N_NODES * 4,      stream);
    hipMemsetAsync(cnt,  0, N_NODES * 4,      stream);
    hipMemsetAsync(gsum, 0, N_GRAPHS * F * 4, stream);
    hipMemsetAsync(gcnt, 0, N_GRAPHS * 4,     stream);

    const int EB = (N_EDGES + 255) / 256;      // 12500
    const int NB = (N_NODES + 255) / 256;      // 391

    k_hist<<<EB, 256, 0, stream>>>(col, ea, deg, cnt);
    k_dinv<<<NB, 256, 0, stream>>>(deg);
    k_scan<<<1, 1024, 0, stream>>>(cnt, offs, cursor);
    k_scatter<<<EB, 256, 0, stream>>>(row, col, ea, deg, cursor, esrc, ewn);
    k_s1<<<NB, 256, 0, stream>>>(x, deg, offs, esrc, ewn, s1);
    k_h1<<<(N_NODES * F + 255) / 256, 256, 0, stream>>>(s1, W1, b1, h1);
    k_agg<<<(N_NODES * F + 255) / 256, 256, 0, stream>>>(h1, deg, offs, esrc, ewn, a1);
    k_h2<<<1024, 256, 0, stream>>>(a1, W2, b2, h1);           // h2 aliases h1 buffer
    k_pool<<<(NB + 3) / 4, 256, 0, stream>>>(h1, bat, gsum, gcnt);
    k_final<<<(N_GRAPHS + 3) / 4, 256, 0, stream>>>(gsum, gcnt, fc1W, fc1b, fc2W, fc2b, out);
}

// Round 3
// 805.629 us; speedup vs baseline: 1.5048x; 1.5048x over previous
//
#include <hip/hip_runtime.h>
#include <math.h>

#define N_NODES  100000
#define N_EDGES  3200000
#define N_GRAPHS 256
#define F        64

// bucketed counting sort params
#define BSHIFT   8
#define BNODES   256                    // nodes per bucket
#define NBKT     391                    // ceil(N_NODES / BNODES)
#define NCH      512                    // edge chunks
#define CHUNK    6250                   // edges per chunk (NCH*CHUNK == N_EDGES)
#define SCAN_M   (NBKT * NCH)           // 200192
#define MAXB     9000                   // LDS-staged edges per bucket (avg 8192, sd ~90)

// JAX default gelu: approximate=True (tanh form)
__device__ __forceinline__ float gelu_f(float x) {
    float x3 = x * x * x;
    float inner = 0.7978845608028654f * (x + 0.044715f * x3);
    return 0.5f * x * (1.0f + tanhf(inner));
}

// ---- pass 1: per-(chunk) LDS histogram over buckets -----------------------
__global__ void __launch_bounds__(256) k_bcount(const int* __restrict__ col,
                                                int* __restrict__ bcnt) {
    __shared__ int cnt[NBKT];
    for (int i = threadIdx.x; i < NBKT; i += 256) cnt[i] = 0;
    __syncthreads();
    int ch = blockIdx.x;
    int base = ch * CHUNK;
    for (int i = threadIdx.x; i < CHUNK; i += 256)
        atomicAdd(&cnt[col[base + i] >> BSHIFT], 1);
    __syncthreads();
    for (int i = threadIdx.x; i < NBKT; i += 256)
        bcnt[i * NCH + ch] = cnt[i];        // bucket-major layout
}

// ---- pass 2: exclusive scan of the (bucket-major) count table -------------
__global__ void __launch_bounds__(1024) k_bscan(const int* __restrict__ bcnt,
                                                int* __restrict__ bcur) {
    __shared__ int sums[1024];
    int t = threadIdx.x;
    const int chunk = (SCAN_M + 1023) / 1024;   // 196
    int b = t * chunk;
    int e = min(b + chunk, SCAN_M);
    int s = 0;
    for (int i = b; i < e; i++) s += bcnt[i];
    sums[t] = s;
    __syncthreads();
    for (int off = 1; off < 1024; off <<= 1) {
        int v = 0;
        if (t >= off) v = sums[t - off];
        __syncthreads();
        if (t >= off) sums[t] += v;
        __syncthreads();
    }
    int run = sums[t] - s;
    for (int i = b; i < e; i++) { int c = bcnt[i]; bcur[i] = run; run += c; }
}

// ---- pass 3: scatter edges into bucket segments (LDS cursors, no global atomics)
__global__ void __launch_bounds__(256) k_bscatter(const int* __restrict__ row,
                                                  const int* __restrict__ col,
                                                  const float* __restrict__ ew,
                                                  const int* __restrict__ bcur,
                                                  unsigned long long* __restrict__ ebuf) {
    __shared__ int cur[NBKT];
    int ch = blockIdx.x;
    for (int i = threadIdx.x; i < NBKT; i += 256) cur[i] = bcur[i * NCH + ch];
    __syncthreads();
    int base = ch * CHUNK;
    for (int i = threadIdx.x; i < CHUNK; i += 256) {
        int c = col[base + i];
        int r = row[base + i];
        float w = ew[base + i];
        int bk = c >> BSHIFT;
        int p = atomicAdd(&cur[bk], 1);     // LDS atomic
        unsigned int hi = ((unsigned)(c & (BNODES - 1)) << 20) | (unsigned)r;
        ebuf[p] = ((unsigned long long)hi << 32) | (unsigned long long)__float_as_uint(w);
    }
}

// ---- pass 4: per-bucket CSR finalize + deg/dinv/y, all in LDS -------------
__global__ void __launch_bounds__(256) k_bbuild(const unsigned long long* __restrict__ ebuf,
                                                const int* __restrict__ bcur,
                                                const float* __restrict__ x,
                                                unsigned long long* __restrict__ csr,
                                                int* __restrict__ offs,
                                                float* __restrict__ dinv,
                                                float* __restrict__ y) {
    __shared__ unsigned long long st[MAXB];
    __shared__ int   cnt[BNODES];
    __shared__ float deg[BNODES];
    __shared__ int   cur[BNODES];
    __shared__ int   sc[BNODES];
    int b = blockIdx.x;
    int t = threadIdx.x;
    int e0 = bcur[b * NCH];
    int e1 = (b == NBKT - 1) ? N_EDGES : bcur[(b + 1) * NCH];
    int len = e1 - e0;
    int sl = min(len, MAXB);
    cnt[t] = 0;
    deg[t] = 0.0f;
    for (int i = t; i < sl; i += 256) st[i] = ebuf[e0 + i];
    __syncthreads();
    for (int i = t; i < len; i += 256) {
        unsigned long long v = (i < MAXB) ? st[i] : ebuf[e0 + i];
        int cl = (int)(v >> 52);            // col_local (hi>>20)
        float w = __uint_as_float((unsigned)v);
        atomicAdd(&cnt[cl], 1);
        atomicAdd(&deg[cl], w);
    }
    __syncthreads();
    int c = cnt[t];
    sc[t] = c;
    __syncthreads();
    for (int off = 1; off < 256; off <<= 1) {
        int v = 0;
        if (t >= off) v = sc[t - off];
        __syncthreads();
        if (t >= off) sc[t] += v;
        __syncthreads();
    }
    int loff = sc[t] - c;                   // exclusive prefix within bucket
    cur[t] = loff;
    int node = (b << BSHIFT) + t;
    if (node < N_NODES) {
        offs[node] = e0 + loff;
        float di = rsqrtf(deg[t] + 1.0f);   // +1 = self-loop weight
        dinv[node] = di;
        y[node] = di * x[node];
    }
    if (b == 0 && t == 0) offs[N_NODES] = N_EDGES;
    __syncthreads();
    for (int i = t; i < len; i += 256) {
        unsigned long long v = (i < MAXB) ? st[i] : ebuf[e0 + i];
        int cl = (int)(v >> 52);
        int p = atomicAdd(&cur[cl], 1);     // LDS atomic
        csr[e0 + p] = v;
    }
}

// ---- layer 1 scalar aggregation: s1[c] = dinv[c]*(sum ew*y[src] + y[c]) ---
__global__ void __launch_bounds__(256) k_s1(const float* __restrict__ y,
                                            const float* __restrict__ dinv,
                                            const int* __restrict__ offs,
                                            const unsigned long long* __restrict__ csr,
                                            float* __restrict__ s1) {
    int c = blockIdx.x * 256 + threadIdx.x;
    if (c >= N_NODES) return;
    int e0 = offs[c], e1 = offs[c + 1];
    float s = y[c];
    for (int j = e0; j < e1; j++) {
        unsigned long long v = csr[j];
        int src = (int)((v >> 32) & 0xFFFFF);
        float w = __uint_as_float((unsigned)v);
        s = fmaf(w, y[src], s);
    }
    s1[c] = s * dinv[c];
}

// ---- h1s[c,f] = dinv[c] * gelu(s1[c]*W1[f] + b1[f]) -----------------------
__global__ void k_h1(const float* __restrict__ s1, const float* __restrict__ dinv,
                     const float* __restrict__ W1, const float* __restrict__ b1,
                     float* __restrict__ h1s) {
    int i = blockIdx.x * blockDim.x + threadIdx.x;
    if (i >= N_NODES * F) return;
    int f = i & (F - 1);
    int c = i >> 6;
    h1s[i] = dinv[c] * gelu_f(fmaf(s1[c], W1[f], b1[f]));
}

// ---- layer 2 aggregation: 4 nodes/wave, 16 lanes x float4 per node --------
__global__ void __launch_bounds__(256) k_agg(const float* __restrict__ h1s,
                                             const float* __restrict__ dinv,
                                             const int* __restrict__ offs,
                                             const unsigned long long* __restrict__ csr,
                                             float* __restrict__ a1) {
    int lane = threadIdx.x & 63;
    int wave = (blockIdx.x * 256 + threadIdx.x) >> 6;
    int node = wave * 4 + (lane >> 4);
    if (node >= N_NODES) return;
    int l4 = (lane & 15) * 4;
    int e0 = offs[node], e1 = offs[node + 1];
    float4 a = make_float4(0.f, 0.f, 0.f, 0.f);
    float4 b = make_float4(0.f, 0.f, 0.f, 0.f);
    int j = e0;
    for (; j + 1 < e1; j += 2) {
        unsigned long long v0 = csr[j], v1 = csr[j + 1];
        const float4 r0 = *(const float4*)(h1s + (int)((v0 >> 32) & 0xFFFFF) * F + l4);
        const float4 r1 = *(const float4*)(h1s + (int)((v1 >> 32) & 0xFFFFF) * F + l4);
        float w0 = __uint_as_float((unsigned)v0);
        float w1 = __uint_as_float((unsigned)v1);
        a.x = fmaf(w0, r0.x, a.x); a.y = fmaf(w0, r0.y, a.y);
        a.z = fmaf(w0, r0.z, a.z); a.w = fmaf(w0, r0.w, a.w);
        b.x = fmaf(w1, r1.x, b.x); b.y = fmaf(w1, r1.y, b.y);
        b.z = fmaf(w1, r1.z, b.z); b.w = fmaf(w1, r1.w, b.w);
    }
    if (j < e1) {
        unsigned long long v0 = csr[j];
        const float4 r0 = *(const float4*)(h1s + (int)((v0 >> 32) & 0xFFFFF) * F + l4);
        float w0 = __uint_as_float((unsigned)v0);
        a.x = fmaf(w0, r0.x, a.x); a.y = fmaf(w0, r0.y, a.y);
        a.z = fmaf(w0, r0.z, a.z); a.w = fmaf(w0, r0.w, a.w);
    }
    const float4 sf = *(const float4*)(h1s + (size_t)node * F + l4);
    float di = dinv[node];
    float4 o;
    o.x = di * (a.x + b.x + sf.x);
    o.y = di * (a.y + b.y + sf.y);
    o.z = di * (a.z + b.z + sf.z);
    o.w = di * (a.w + b.w + sf.w);
    *(float4*)(a1 + (size_t)node * F + l4) = o;
}

// ---- layer 2 matmul [N,64]@[64,64] + bias + gelu --------------------------
__global__ void __launch_bounds__(256) k_h2(const float* __restrict__ a1,
                                            const float* __restrict__ W2,
                                            const float* __restrict__ b2,
                                            float* __restrict__ h2) {
    __shared__ float sW[F * F];
    __shared__ float sb[F];
    __shared__ float sa[4][F];
    for (int i = threadIdx.x; i < F * F; i += 256) sW[i] = W2[i];
    if (threadIdx.x < F) sb[threadIdx.x] = b2[threadIdx.x];
    __syncthreads();
    int lane = threadIdx.x & 63;
    int wv   = threadIdx.x >> 6;
    for (int node = blockIdx.x * 4 + wv; node < N_NODES; node += gridDim.x * 4) {
        sa[wv][lane] = a1[node * F + lane];   // same-wave write/read
        float acc = sb[lane];
#pragma unroll
        for (int k = 0; k < F; k++) acc = fmaf(sa[wv][k], sW[k * F + lane], acc);
        h2[node * F + lane] = gelu_f(acc);
    }
}

// ---- pooling: batch sorted -> run-length accumulate, rare atomics ---------
__global__ void __launch_bounds__(256) k_pool(const float* __restrict__ h2,
                                              const int* __restrict__ batch,
                                              float* __restrict__ gsum,
                                              float* __restrict__ gcnt) {
    int gw   = (blockIdx.x * 256 + threadIdx.x) >> 6;
    int lane = threadIdx.x & 63;
    const int PCHUNK = 256;
    int n0 = gw * PCHUNK;
    if (n0 >= N_NODES) return;
    int n1 = min(n0 + PCHUNK, N_NODES);
    int curg = batch[n0];
    float run = 0.0f;
    int   rl  = 0;
    for (int n = n0; n < n1; n++) {
        int g = batch[n];
        if (g != curg) {
            atomicAdd(&gsum[curg * F + lane], run);
            if (lane == 0) atomicAdd(&gcnt[curg], (float)rl);
            run = 0.0f; rl = 0; curg = g;
        }
        run += h2[n * F + lane];
        rl++;
    }
    atomicAdd(&gsum[curg * F + lane], run);
    if (lane == 0) atomicAdd(&gcnt[curg], (float)rl);
}

// ---- final MLP: one wave per graph ----------------------------------------
__global__ void __launch_bounds__(256) k_final(const float* __restrict__ gsum,
                                               const float* __restrict__ gcnt,
                                               const float* __restrict__ fc1W,
                                               const float* __restrict__ fc1b,
                                               const float* __restrict__ fc2W,
                                               const float* __restrict__ fc2b,
                                               float* __restrict__ out) {
    __shared__ float sm[4][F];
    int lane = threadIdx.x & 63;
    int wv   = threadIdx.x >> 6;
    int g = blockIdx.x * 4 + wv;
    if (g >= N_GRAPHS) return;
    float c = gcnt[g];
    float m = gsum[g * F + lane] / fmaxf(c, 1.0f);
    sm[wv][lane] = m;
    float o = 0.0f;
    if (lane < 32) {
        float acc = fc1b[lane];
#pragma unroll
        for (int k = 0; k < F; k++) acc = fmaf(sm[wv][k], fc1W[k * 32 + lane], acc);
        o = gelu_f(acc) * fc2W[lane];
    }
    for (int off = 32; off; off >>= 1) o += __shfl_down(o, off);
    if (lane == 0) out[g] = o + fc2b[0];
}

// ---------------------------------------------------------------------------

extern "C" void kernel_launch(void* const* d_in, const int* in_sizes, int n_in,
                              void* d_out, int out_size, void* d_ws, size_t ws_size,
                              hipStream_t stream) {
    const float* x    = (const float*)d_in[0];
    const int*   ei   = (const int*)  d_in[1];   // [2, E]
    const float* ea   = (const float*)d_in[2];
    const int*   bat  = (const int*)  d_in[3];
    const float* W1   = (const float*)d_in[4];
    const float* b1   = (const float*)d_in[5];
    const float* W2   = (const float*)d_in[6];
    const float* b2   = (const float*)d_in[7];
    const float* fc1W = (const float*)d_in[8];
    const float* fc1b = (const float*)d_in[9];
    const float* fc2W = (const float*)d_in[10];
    const float* fc2b = (const float*)d_in[11];
    float* out = (float*)d_out;

    const int* row = ei;
    const int* col = ei + N_EDGES;

    size_t off = 0;
    auto alloc = [&](size_t bytes) -> void* {
        void* p = (char*)d_ws + off;
        off = (off + bytes + 255) & ~(size_t)255;
        return p;
    };
    int*   bcnt = (int*)alloc((size_t)SCAN_M * 4);                 // 800 KB
    int*   bcur = (int*)alloc((size_t)SCAN_M * 4);                 // 800 KB
    unsigned long long* ebuf = (unsigned long long*)alloc((size_t)N_EDGES * 8);  // 25.6 MB
    unsigned long long* csr  = (unsigned long long*)alloc((size_t)N_EDGES * 8);  // 25.6 MB
    int*   offs = (int*)  alloc((size_t)(N_NODES + 1) * 4);
    float* dinv = (float*)alloc((size_t)N_NODES * 4);
    float* yv   = (float*)alloc((size_t)N_NODES * 4);
    float* s1   = (float*)alloc((size_t)N_NODES * 4);
    float* h1s  = (float*)alloc((size_t)N_NODES * F * 4);          // 25.6 MB; reused for h2
    float* a1   = (float*)ebuf;                                    // alias: ebuf dead after k_bbuild
    float* gsum = (float*)alloc((size_t)N_GRAPHS * F * 4);
    float* gcnt = (float*)alloc((size_t)N_GRAPHS * 4);
    (void)ws_size; (void)n_in; (void)in_sizes; (void)out_size;

    hipMemsetAsync(gsum, 0, N_GRAPHS * F * 4, stream);
    hipMemsetAsync(gcnt, 0, N_GRAPHS * 4,     stream);

    k_bcount <<<NCH, 256, 0, stream>>>(col, bcnt);
    k_bscan  <<<1, 1024, 0, stream>>>(bcnt, bcur);
    k_bscatter<<<NCH, 256, 0, stream>>>(row, col, ea, bcur, ebuf);
    k_bbuild <<<NBKT, 256, 0, stream>>>(ebuf, bcur, x, csr, offs, dinv, yv);
    k_s1     <<<(N_NODES + 255) / 256, 256, 0, stream>>>(yv, dinv, offs, csr, s1);
    k_h1     <<<(N_NODES * F + 255) / 256, 256, 0, stream>>>(s1, dinv, W1, b1, h1s);
    // one wave per 4 nodes -> N_NODES*16 threads (R2 bug: was /4/64, only 6k nodes covered)
    k_agg    <<<(N_NODES * 16 + 255) / 256, 256, 0, stream>>>(h1s, dinv, offs, csr, a1);
    k_h2     <<<1024, 256, 0, stream>>>(a1, W2, b2, h1s);          // h2 into h1s buffer
    k_pool   <<<((N_NODES + 255) / 256 + 3) / 4, 256, 0, stream>>>(h1s, bat, gsum, gcnt);
    k_final  <<<(N_GRAPHS + 3) / 4, 256, 0, stream>>>(gsum, gcnt, fc1W, fc1b, fc2W, fc2b, out);
}

// Round 4
// 493.897 us; speedup vs baseline: 2.4546x; 1.6312x over previous
//
#include <hip/hip_runtime.h>
#include <math.h>

#define N_NODES  100000
#define N_EDGES  3200000
#define N_GRAPHS 256
#define F        64

// bucketed counting sort params
#define BSHIFT   8
#define BNODES   256                    // nodes per bucket
#define NBKT     391                    // ceil(N_NODES / BNODES)
#define NCH      512                    // edge chunks
#define CHUNK    6250                   // edges per chunk (NCH*CHUNK == N_EDGES)
#define MAXB     9000                   // LDS-staged edges per bucket (avg 8192, sd ~90)

// JAX default gelu: approximate=True (tanh form)
__device__ __forceinline__ float gelu_f(float x) {
    float x3 = x * x * x;
    float inner = 0.7978845608028654f * (x + 0.044715f * x3);
    return 0.5f * x * (1.0f + tanhf(inner));
}

// ---- pass 1: per-(chunk) LDS histogram over buckets -----------------------
__global__ void __launch_bounds__(256) k_bcount(const int* __restrict__ col,
                                                int* __restrict__ bcnt) {
    __shared__ int cnt[NBKT];
    for (int i = threadIdx.x; i < NBKT; i += 256) cnt[i] = 0;
    __syncthreads();
    int ch = blockIdx.x;
    int base = ch * CHUNK;
    for (int i = threadIdx.x; i < CHUNK; i += 256)
        atomicAdd(&cnt[col[base + i] >> BSHIFT], 1);
    __syncthreads();
    for (int i = threadIdx.x; i < NBKT; i += 256)
        bcnt[i * NCH + ch] = cnt[i];        // bucket-major layout
}

// ---- pass 2a: per-bucket scan of 512 chunk-counts (391 parallel blocks) ---
__global__ void __launch_bounds__(256) k_bscan_local(const int* __restrict__ bcnt,
                                                     int* __restrict__ brel,
                                                     int* __restrict__ btot) {
    __shared__ int sums[256];
    int b = blockIdx.x;
    int t = threadIdx.x;
    int i0 = b * NCH + 2 * t;
    int c0 = bcnt[i0], c1 = bcnt[i0 + 1];
    int s = c0 + c1;
    sums[t] = s;
    __syncthreads();
    for (int off = 1; off < 256; off <<= 1) {
        int v = 0;
        if (t >= off) v = sums[t - off];
        __syncthreads();
        if (t >= off) sums[t] += v;
        __syncthreads();
    }
    int excl = sums[t] - s;
    brel[i0]     = excl;
    brel[i0 + 1] = excl + c0;
    if (t == 255) btot[b] = sums[255];
}

// ---- pass 2b: scan 391 bucket totals (one tiny block) ---------------------
__global__ void __launch_bounds__(512) k_bscan_base(const int* __restrict__ btot,
                                                    int* __restrict__ bbase) {
    __shared__ int sums[512];
    int t = threadIdx.x;
    int v0 = (t < NBKT) ? btot[t] : 0;
    sums[t] = v0;
    __syncthreads();
    for (int off = 1; off < 512; off <<= 1) {
        int v = 0;
        if (t >= off) v = sums[t - off];
        __syncthreads();
        if (t >= off) sums[t] += v;
        __syncthreads();
    }
    int excl = sums[t] - v0;
    if (t < NBKT) bbase[t] = excl;
    if (t == NBKT - 1) bbase[NBKT] = excl + v0;   // == N_EDGES
}

// ---- pass 3: scatter edges into bucket segments (LDS cursors, no global atomics)
__global__ void __launch_bounds__(256) k_bscatter(const int* __restrict__ row,
                                                  const int* __restrict__ col,
                                                  const float* __restrict__ ew,
                                                  const int* __restrict__ brel,
                                                  const int* __restrict__ bbase,
                                                  unsigned long long* __restrict__ ebuf) {
    __shared__ int cur[NBKT];
    int ch = blockIdx.x;
    for (int i = threadIdx.x; i < NBKT; i += 256)
        cur[i] = bbase[i] + brel[i * NCH + ch];
    __syncthreads();
    int base = ch * CHUNK;
    for (int i = threadIdx.x; i < CHUNK; i += 256) {
        int c = col[base + i];
        int r = row[base + i];
        float w = ew[base + i];
        int bk = c >> BSHIFT;
        int p = atomicAdd(&cur[bk], 1);     // LDS atomic
        unsigned int hi = ((unsigned)(c & (BNODES - 1)) << 20) | (unsigned)r;
        ebuf[p] = ((unsigned long long)hi << 32) | (unsigned long long)__float_as_uint(w);
    }
}

// ---- pass 4: per-bucket CSR finalize + deg/dinv/y, all in LDS -------------
__global__ void __launch_bounds__(256) k_bbuild(const unsigned long long* __restrict__ ebuf,
                                                const int* __restrict__ bbase,
                                                const float* __restrict__ x,
                                                unsigned long long* __restrict__ csr,
                                                int* __restrict__ offs,
                                                float* __restrict__ dinv,
                                                float* __restrict__ y) {
    __shared__ unsigned long long st[MAXB];
    __shared__ int   cnt[BNODES];
    __shared__ float deg[BNODES];
    __shared__ int   cur[BNODES];
    __shared__ int   sc[BNODES];
    int b = blockIdx.x;
    int t = threadIdx.x;
    int e0 = bbase[b];
    int e1 = bbase[b + 1];
    int len = e1 - e0;
    int sl = min(len, MAXB);
    cnt[t] = 0;
    deg[t] = 0.0f;
    for (int i = t; i < sl; i += 256) st[i] = ebuf[e0 + i];
    __syncthreads();
    for (int i = t; i < len; i += 256) {
        unsigned long long v = (i < MAXB) ? st[i] : ebuf[e0 + i];
        int cl = (int)(v >> 52);            // col_local (hi>>20)
        float w = __uint_as_float((unsigned)v);
        atomicAdd(&cnt[cl], 1);
        atomicAdd(&deg[cl], w);
    }
    __syncthreads();
    int c = cnt[t];
    sc[t] = c;
    __syncthreads();
    for (int off = 1; off < 256; off <<= 1) {
        int v = 0;
        if (t >= off) v = sc[t - off];
        __syncthreads();
        if (t >= off) sc[t] += v;
        __syncthreads();
    }
    int loff = sc[t] - c;                   // exclusive prefix within bucket
    cur[t] = loff;
    int node = (b << BSHIFT) + t;
    if (node < N_NODES) {
        offs[node] = e0 + loff;
        float di = rsqrtf(deg[t] + 1.0f);   // +1 = self-loop weight
        dinv[node] = di;
        y[node] = di * x[node];
    }
    if (b == 0 && t == 0) offs[N_NODES] = N_EDGES;
    __syncthreads();
    for (int i = t; i < len; i += 256) {
        unsigned long long v = (i < MAXB) ? st[i] : ebuf[e0 + i];
        int cl = (int)(v >> 52);
        int p = atomicAdd(&cur[cl], 1);     // LDS atomic
        csr[e0 + p] = v;
    }
}

// ---- layer 1 scalar aggregation: s1[c] = dinv[c]*(sum ew*y[src] + y[c]) ---
__global__ void __launch_bounds__(256) k_s1(const float* __restrict__ y,
                                            const float* __restrict__ dinv,
                                            const int* __restrict__ offs,
                                            const unsigned long long* __restrict__ csr,
                                            float* __restrict__ s1) {
    int c = blockIdx.x * 256 + threadIdx.x;
    if (c >= N_NODES) return;
    int e0 = offs[c], e1 = offs[c + 1];
    float s = y[c];
    for (int j = e0; j < e1; j++) {
        unsigned long long v = csr[j];
        int src = (int)((v >> 32) & 0xFFFFF);
        float w = __uint_as_float((unsigned)v);
        s = fmaf(w, y[src], s);
    }
    s1[c] = s * dinv[c];
}

// ---- h1s[c,f] = dinv[c] * gelu(s1[c]*W1[f] + b1[f]) -----------------------
__global__ void k_h1(const float* __restrict__ s1, const float* __restrict__ dinv,
                     const float* __restrict__ W1, const float* __restrict__ b1,
                     float* __restrict__ h1s) {
    int i = blockIdx.x * blockDim.x + threadIdx.x;
    if (i >= N_NODES * F) return;
    int f = i & (F - 1);
    int c = i >> 6;
    h1s[i] = dinv[c] * gelu_f(fmaf(s1[c], W1[f], b1[f]));
}

// ---- layer 2 aggregation: 4 nodes/wave, 16 lanes x float4 per node --------
__global__ void __launch_bounds__(256) k_agg(const float* __restrict__ h1s,
                                             const float* __restrict__ dinv,
                                             const int* __restrict__ offs,
                                             const unsigned long long* __restrict__ csr,
                                             float* __restrict__ a1) {
    int lane = threadIdx.x & 63;
    int wave = (blockIdx.x * 256 + threadIdx.x) >> 6;
    int node = wave * 4 + (lane >> 4);
    if (node >= N_NODES) return;
    int l4 = (lane & 15) * 4;
    int e0 = offs[node], e1 = offs[node + 1];
    float4 a = make_float4(0.f, 0.f, 0.f, 0.f);
    float4 b = make_float4(0.f, 0.f, 0.f, 0.f);
    int j = e0;
    for (; j + 1 < e1; j += 2) {
        unsigned long long v0 = csr[j], v1 = csr[j + 1];
        const float4 r0 = *(const float4*)(h1s + (int)((v0 >> 32) & 0xFFFFF) * F + l4);
        const float4 r1 = *(const float4*)(h1s + (int)((v1 >> 32) & 0xFFFFF) * F + l4);
        float w0 = __uint_as_float((unsigned)v0);
        float w1 = __uint_as_float((unsigned)v1);
        a.x = fmaf(w0, r0.x, a.x); a.y = fmaf(w0, r0.y, a.y);
        a.z = fmaf(w0, r0.z, a.z); a.w = fmaf(w0, r0.w, a.w);
        b.x = fmaf(w1, r1.x, b.x); b.y = fmaf(w1, r1.y, b.y);
        b.z = fmaf(w1, r1.z, b.z); b.w = fmaf(w1, r1.w, b.w);
    }
    if (j < e1) {
        unsigned long long v0 = csr[j];
        const float4 r0 = *(const float4*)(h1s + (int)((v0 >> 32) & 0xFFFFF) * F + l4);
        float w0 = __uint_as_float((unsigned)v0);
        a.x = fmaf(w0, r0.x, a.x); a.y = fmaf(w0, r0.y, a.y);
        a.z = fmaf(w0, r0.z, a.z); a.w = fmaf(w0, r0.w, a.w);
    }
    const float4 sf = *(const float4*)(h1s + (size_t)node * F + l4);
    float di = dinv[node];
    float4 o;
    o.x = di * (a.x + b.x + sf.x);
    o.y = di * (a.y + b.y + sf.y);
    o.z = di * (a.z + b.z + sf.z);
    o.w = di * (a.w + b.w + sf.w);
    *(float4*)(a1 + (size_t)node * F + l4) = o;
}

// ---- layer 2 matmul [N,64]@[64,64] + bias + gelu --------------------------
__global__ void __launch_bounds__(256) k_h2(const float* __restrict__ a1,
                                            const float* __restrict__ W2,
                                            const float* __restrict__ b2,
                                            float* __restrict__ h2) {
    __shared__ float sW[F * F];
    __shared__ float sb[F];
    __shared__ float sa[4][F];
    for (int i = threadIdx.x; i < F * F; i += 256) sW[i] = W2[i];
    if (threadIdx.x < F) sb[threadIdx.x] = b2[threadIdx.x];
    __syncthreads();
    int lane = threadIdx.x & 63;
    int wv   = threadIdx.x >> 6;
    for (int node = blockIdx.x * 4 + wv; node < N_NODES; node += gridDim.x * 4) {
        sa[wv][lane] = a1[node * F + lane];   // same-wave write/read
        float acc = sb[lane];
#pragma unroll
        for (int k = 0; k < F; k++) acc = fmaf(sa[wv][k], sW[k * F + lane], acc);
        h2[node * F + lane] = gelu_f(acc);
    }
}

// ---- pooling: batch sorted -> run-length accumulate, rare atomics ---------
__global__ void __launch_bounds__(256) k_pool(const float* __restrict__ h2,
                                              const int* __restrict__ batch,
                                              float* __restrict__ gsum,
                                              float* __restrict__ gcnt) {
    int gw   = (blockIdx.x * 256 + threadIdx.x) >> 6;
    int lane = threadIdx.x & 63;
    const int PCHUNK = 256;
    int n0 = gw * PCHUNK;
    if (n0 >= N_NODES) return;
    int n1 = min(n0 + PCHUNK, N_NODES);
    int curg = batch[n0];
    float run = 0.0f;
    int   rl  = 0;
    for (int n = n0; n < n1; n++) {
        int g = batch[n];
        if (g != curg) {
            atomicAdd(&gsum[curg * F + lane], run);
            if (lane == 0) atomicAdd(&gcnt[curg], (float)rl);
            run = 0.0f; rl = 0; curg = g;
        }
        run += h2[n * F + lane];
        rl++;
    }
    atomicAdd(&gsum[curg * F + lane], run);
    if (lane == 0) atomicAdd(&gcnt[curg], (float)rl);
}

// ---- final MLP: one wave per graph ----------------------------------------
__global__ void __launch_bounds__(256) k_final(const float* __restrict__ gsum,
                                               const float* __restrict__ gcnt,
                                               const float* __restrict__ fc1W,
                                               const float* __restrict__ fc1b,
                                               const float* __restrict__ fc2W,
                                               const float* __restrict__ fc2b,
                                               float* __restrict__ out) {
    __shared__ float sm[4][F];
    int lane = threadIdx.x & 63;
    int wv   = threadIdx.x >> 6;
    int g = blockIdx.x * 4 + wv;
    if (g >= N_GRAPHS) return;
    float c = gcnt[g];
    float m = gsum[g * F + lane] / fmaxf(c, 1.0f);
    sm[wv][lane] = m;
    float o = 0.0f;
    if (lane < 32) {
        float acc = fc1b[lane];
#pragma unroll
        for (int k = 0; k < F; k++) acc = fmaf(sm[wv][k], fc1W[k * 32 + lane], acc);
        o = gelu_f(acc) * fc2W[lane];
    }
    for (int off = 32; off; off >>= 1) o += __shfl_down(o, off);
    if (lane == 0) out[g] = o + fc2b[0];
}

// ---------------------------------------------------------------------------

extern "C" void kernel_launch(void* const* d_in, const int* in_sizes, int n_in,
                              void* d_out, int out_size, void* d_ws, size_t ws_size,
                              hipStream_t stream) {
    const float* x    = (const float*)d_in[0];
    const int*   ei   = (const int*)  d_in[1];   // [2, E]
    const float* ea   = (const float*)d_in[2];
    const int*   bat  = (const int*)  d_in[3];
    const float* W1   = (const float*)d_in[4];
    const float* b1   = (const float*)d_in[5];
    const float* W2   = (const float*)d_in[6];
    const float* b2   = (const float*)d_in[7];
    const float* fc1W = (const float*)d_in[8];
    const float* fc1b = (const float*)d_in[9];
    const float* fc2W = (const float*)d_in[10];
    const float* fc2b = (const float*)d_in[11];
    float* out = (float*)d_out;

    const int* row = ei;
    const int* col = ei + N_EDGES;

    size_t off = 0;
    auto alloc = [&](size_t bytes) -> void* {
        void* p = (char*)d_ws + off;
        off = (off + bytes + 255) & ~(size_t)255;
        return p;
    };
    int*   bcnt  = (int*)alloc((size_t)NBKT * NCH * 4);            // 800 KB
    int*   brel  = (int*)alloc((size_t)NBKT * NCH * 4);            // 800 KB
    int*   btot  = (int*)alloc((size_t)NBKT * 4);
    int*   bbase = (int*)alloc((size_t)(NBKT + 1) * 4);
    unsigned long long* ebuf = (unsigned long long*)alloc((size_t)N_EDGES * 8);  // 25.6 MB
    unsigned long long* csr  = (unsigned long long*)alloc((size_t)N_EDGES * 8);  // 25.6 MB
    int*   offs = (int*)  alloc((size_t)(N_NODES + 1) * 4);
    float* dinv = (float*)alloc((size_t)N_NODES * 4);
    float* yv   = (float*)alloc((size_t)N_NODES * 4);
    float* s1   = (float*)alloc((size_t)N_NODES * 4);
    float* h1s  = (float*)alloc((size_t)N_NODES * F * 4);          // 25.6 MB; reused for h2
    float* a1   = (float*)ebuf;                                    // alias: ebuf dead after k_bbuild
    float* gsum = (float*)alloc((size_t)N_GRAPHS * F * 4);
    float* gcnt = (float*)alloc((size_t)N_GRAPHS * 4);
    (void)ws_size; (void)n_in; (void)in_sizes; (void)out_size;

    hipMemsetAsync(gsum, 0, N_GRAPHS * F * 4, stream);
    hipMemsetAsync(gcnt, 0, N_GRAPHS * 4,     stream);

    k_bcount     <<<NCH, 256, 0, stream>>>(col, bcnt);
    k_bscan_local<<<NBKT, 256, 0, stream>>>(bcnt, brel, btot);
    k_bscan_base <<<1, 512, 0, stream>>>(btot, bbase);
    k_bscatter   <<<NCH, 256, 0, stream>>>(row, col, ea, brel, bbase, ebuf);
    k_bbuild     <<<NBKT, 256, 0, stream>>>(ebuf, bbase, x, csr, offs, dinv, yv);
    k_s1         <<<(N_NODES + 255) / 256, 256, 0, stream>>>(yv, dinv, offs, csr, s1);
    k_h1         <<<(N_NODES * F + 255) / 256, 256, 0, stream>>>(s1, dinv, W1, b1, h1s);
    k_agg        <<<(N_NODES * 16 + 255) / 256, 256, 0, stream>>>(h1s, dinv, offs, csr, a1);
    k_h2         <<<1024, 256, 0, stream>>>(a1, W2, b2, h1s);      // h2 into h1s buffer
    k_pool       <<<((N_NODES + 255) / 256 + 3) / 4, 256, 0, stream>>>(h1s, bat, gsum, gcnt);
    k_final      <<<(N_GRAPHS + 3) / 4, 256, 0, stream>>>(gsum, gcnt, fc1W, fc1b, fc2W, fc2b, out);
}